// Round 1
// baseline (563.376 us; speedup 1.0000x reference)
//
#include <hip/hip_runtime.h>

// out[b,h,w,i,c] = inputs[b,h,w,i] * u[i,c],  u = beta^2 / rowsum(beta^2)
// B=8 H=128 W=128 D=64 C=16. Output 512 MiB fp32 -> write-BW bound.
// v2: hoist u-fragment to a register (thread's (i,q) is grid-stride invariant
//     since stride % 256 == 0), unroll-8 with loads batched ahead of stores
//     for MLP, fully-resident 2048-block grid (64 iters/thread).

#define Dd 64
#define Cc 16

__global__ __launch_bounds__(256) void DS2_62466004353281_kernel(
    const float* __restrict__ inputs,   // [B*H*W*D] = 8388608
    const float* __restrict__ beta,     // [D*C] = 1024
    float* __restrict__ out,            // [B*H*W*D*C] = 134217728
    int n_quads)                        // out float4 count = 33554432
{
    __shared__ float u[Dd * Cc];        // 4 KiB normalized squared weights
    const int t = threadIdx.x;

    // threads 0..63 each compute one row of u
    if (t < Dd) {
        float b2[Cc];
        float s = 0.f;
#pragma unroll
        for (int c = 0; c < Cc; ++c) {
            float b = beta[t * Cc + c];
            b2[c] = b * b;
            s += b2[c];
        }
        float inv = 1.0f / s;
#pragma unroll
        for (int c = 0; c < Cc; ++c) u[t * Cc + c] = b2[c] * inv;
    }
    __syncthreads();

    const float4* __restrict__ u4 = (const float4*)u;
    float4* __restrict__ out4 = (float4*)out;

    const int stride  = gridDim.x * blockDim.x;   // quads/pass; multiple of 256
    const int base    = blockIdx.x * blockDim.x + t;

    // (i,q) invariant across grid-stride iterations -> read u fragment ONCE.
    // i = (idx>>2) & 63, q = idx & 3 are the same for every idx = base + j*stride.
    const float4 uu = u4[(((base >> 2) & (Dd - 1)) << 2) | (base & 3)];

    const int estride = stride >> 2;              // input elems/pass
    int elem = base >> 2;
    int idx  = base;

    // main loop: 8 independent loads issued before any dependent store
    const int full = n_quads - 7 * stride;        // idx < full => all 8 in range
    while (idx < full) {
        const float x0 = inputs[elem];
        const float x1 = inputs[elem +     estride];
        const float x2 = inputs[elem + 2 * estride];
        const float x3 = inputs[elem + 3 * estride];
        const float x4 = inputs[elem + 4 * estride];
        const float x5 = inputs[elem + 5 * estride];
        const float x6 = inputs[elem + 6 * estride];
        const float x7 = inputs[elem + 7 * estride];

        float4 o;
        o.x = x0 * uu.x; o.y = x0 * uu.y; o.z = x0 * uu.z; o.w = x0 * uu.w;
        out4[idx             ] = o;
        o.x = x1 * uu.x; o.y = x1 * uu.y; o.z = x1 * uu.z; o.w = x1 * uu.w;
        out4[idx +     stride] = o;
        o.x = x2 * uu.x; o.y = x2 * uu.y; o.z = x2 * uu.z; o.w = x2 * uu.w;
        out4[idx + 2 * stride] = o;
        o.x = x3 * uu.x; o.y = x3 * uu.y; o.z = x3 * uu.z; o.w = x3 * uu.w;
        out4[idx + 3 * stride] = o;
        o.x = x4 * uu.x; o.y = x4 * uu.y; o.z = x4 * uu.z; o.w = x4 * uu.w;
        out4[idx + 4 * stride] = o;
        o.x = x5 * uu.x; o.y = x5 * uu.y; o.z = x5 * uu.z; o.w = x5 * uu.w;
        out4[idx + 5 * stride] = o;
        o.x = x6 * uu.x; o.y = x6 * uu.y; o.z = x6 * uu.z; o.w = x6 * uu.w;
        out4[idx + 6 * stride] = o;
        o.x = x7 * uu.x; o.y = x7 * uu.y; o.z = x7 * uu.z; o.w = x7 * uu.w;
        out4[idx + 7 * stride] = o;

        idx  += 8 * stride;
        elem += 8 * estride;
    }

    // tail (never taken at the fixed problem size; kept for generality)
    for (; idx < n_quads; idx += stride, elem += estride) {
        const float x = inputs[elem];
        float4 o;
        o.x = x * uu.x; o.y = x * uu.y; o.z = x * uu.z; o.w = x * uu.w;
        out4[idx] = o;
    }
}

extern "C" void kernel_launch(void* const* d_in, const int* in_sizes, int n_in,
                              void* d_out, int out_size, void* d_ws, size_t ws_size,
                              hipStream_t stream) {
    const float* inputs = (const float*)d_in[0];
    const float* beta   = (const float*)d_in[1];
    float* out          = (float*)d_out;

    const int n_quads = out_size / 4;   // 33,554,432 float4 stores
    // 2048 blocks = 8 blocks/CU fully resident; 64 grid-stride iters/thread.
    dim3 grid(2048), block(256);
    DS2_62466004353281_kernel<<<grid, block, 0, stream>>>(inputs, beta, out, n_quads);
}